// Round 1
// baseline (410.976 us; speedup 1.0000x reference)
//
#include <hip/hip_runtime.h>
#include <cstdint>
#include <cstddef>

typedef __attribute__((ext_vector_type(8))) __bf16 bf16x8;
typedef __attribute__((ext_vector_type(4))) __bf16 bf16x4;
typedef __attribute__((ext_vector_type(4))) float f32x4;

#define B_ 4
#define T_ 2048
#define C_ 1024
#define H_ 16
#define D_ 64

// ---------------------------------------------------------------- cast f32->bf16
__global__ __launch_bounds__(256) void castk(const float* __restrict__ in,
                                             __bf16* __restrict__ out, int n) {
  int i = (blockIdx.x * blockDim.x + threadIdx.x) * 4;
  if (i >= n) return;
  float4 f = *reinterpret_cast<const float4*>(in + i);
  bf16x4 o;
  o[0] = (__bf16)f.x; o[1] = (__bf16)f.y; o[2] = (__bf16)f.z; o[3] = (__bf16)f.w;
  *reinterpret_cast<bf16x4*>(out + i) = o;
}

// ---------------------------------------------------------------- async global->LDS
__device__ __forceinline__ void gload_lds16(const __bf16* g, __bf16* lds) {
  __builtin_amdgcn_global_load_lds(
      (const __attribute__((address_space(1))) void*)g,
      (__attribute__((address_space(3))) void*)lds, 16, 0, 0);
}

// ---------------------------------------------------------------- GEMM  C = A * Bt^T
// A: [M][K] bf16 row-major, Bt: [N][K] bf16 row-major (torch Linear weight layout)
// m97 structure: 128x128 tile, BK=64, 4 waves (2x2), 16x16x32 bf16 MFMA.
template <typename OUTT, bool BIAS>
__device__ __forceinline__ void gemm_bt_body(const __bf16* __restrict__ A,
                                             const __bf16* __restrict__ Bt,
                                             OUTT* __restrict__ Cp,
                                             const float* __restrict__ bias,
                                             int M, int N, int K) {
  constexpr int BK = 64;
  __shared__ __bf16 As[128 * BK];
  __shared__ __bf16 Bs[128 * BK];
  const int tid = threadIdx.x;
  const int w = tid >> 6, l = tid & 63;
  const int wr = w >> 1, wc = w & 1;
  const int lr = l & 15, lg = l >> 4;
  const int m0 = blockIdx.y * 128, n0 = blockIdx.x * 128;
  const int srow = l >> 3, scol = (l & 7) * 8;  // staging: 8 rows x 64 cols per 1KB chunk

  f32x4 acc[4][4] = {};

  for (int k0 = 0; k0 < K; k0 += BK) {
#pragma unroll
    for (int it = 0; it < 4; ++it) {
      const int c = w * 4 + it;  // chunk 0..15, wave-uniform
      gload_lds16(A + (size_t)(m0 + 8 * c + srow) * K + k0 + scol, As + c * 512);
      gload_lds16(Bt + (size_t)(n0 + 8 * c + srow) * K + k0 + scol, Bs + c * 512);
    }
    __syncthreads();  // drains vmcnt before barrier
    bf16x8 af[4][2], bfv[4][2];
#pragma unroll
    for (int m = 0; m < 4; ++m)
#pragma unroll
      for (int kk = 0; kk < 2; ++kk)
        af[m][kk] = *reinterpret_cast<const bf16x8*>(As + (wr * 64 + m * 16 + lr) * BK + kk * 32 + lg * 8);
#pragma unroll
    for (int n = 0; n < 4; ++n)
#pragma unroll
      for (int kk = 0; kk < 2; ++kk)
        bfv[n][kk] = *reinterpret_cast<const bf16x8*>(Bs + (wc * 64 + n * 16 + lr) * BK + kk * 32 + lg * 8);
#pragma unroll
    for (int kk = 0; kk < 2; ++kk)
#pragma unroll
      for (int m = 0; m < 4; ++m)
#pragma unroll
        for (int n = 0; n < 4; ++n)
          acc[m][n] = __builtin_amdgcn_mfma_f32_16x16x32_bf16(af[m][kk], bfv[n][kk], acc[m][n], 0, 0, 0);
    __syncthreads();
  }
  // epilogue: C/D layout col=lane&15, row=(lane>>4)*4+reg (m89/m91-verified)
#pragma unroll
  for (int m = 0; m < 4; ++m)
#pragma unroll
    for (int n = 0; n < 4; ++n) {
      const int col = n0 + wc * 64 + n * 16 + lr;
      float bv = 0.f;
      if (BIAS) bv = bias[col];
#pragma unroll
      for (int j = 0; j < 4; ++j) {
        const int row = m0 + wr * 64 + m * 16 + lg * 4 + j;
        Cp[(size_t)row * N + col] = (OUTT)(acc[m][n][j] + bv);
      }
    }
}

__global__ __launch_bounds__(256) void gemm_qkv(const __bf16* __restrict__ xb,
    const __bf16* __restrict__ wq, const __bf16* __restrict__ wk, const __bf16* __restrict__ wv,
    __bf16* __restrict__ q, __bf16* __restrict__ k, __bf16* __restrict__ v) {
  const __bf16* W = (blockIdx.z == 0) ? wq : (blockIdx.z == 1) ? wk : wv;
  __bf16* O = (blockIdx.z == 0) ? q : (blockIdx.z == 1) ? k : v;
  gemm_bt_body<__bf16, false>(xb, W, O, nullptr, B_ * T_, C_, C_);
}

__global__ __launch_bounds__(256) void gemm_proj(const __bf16* __restrict__ ao,
    const __bf16* __restrict__ wp, float* __restrict__ out, const float* __restrict__ bp) {
  gemm_bt_body<float, true>(ao, wp, out, bp, B_ * T_, C_, C_);
}

// ---------------------------------------------------------------- flash attention
// One block = one (b,h) x 128 q-rows. 4 waves x 32 rows. KVBLK=64, causal.
__global__ __launch_bounds__(256) void attn_fwd(const __bf16* __restrict__ qb,
                                                const __bf16* __restrict__ kb,
                                                const __bf16* __restrict__ vb,
                                                __bf16* __restrict__ ao) {
  __shared__ __bf16 Vts[64 * 72];       // V transposed: [d][kv], stride 72 (pad)
  __shared__ __bf16 Pls[4 * 32 * 72];   // per-wave P tiles, stride 72
  const int tid = threadIdx.x;
  const int w = tid >> 6, l = tid & 63;
  const int lr = l & 15, lg = l >> 4;
  const int bh = blockIdx.y;
  const int b = bh >> 4, h = bh & 15;
  const int q0 = blockIdx.x * 128;
  const size_t rowbase = (size_t)b * T_;
  const int hoff = h * D_;
  const float scale = 0.03125f;  // C^-0.5 = 1/32

  // Q fragments (A-operand): row = lr, k-chunk = lg*8
  bf16x8 qf[2][2];
#pragma unroll
  for (int im = 0; im < 2; ++im)
#pragma unroll
    for (int kk = 0; kk < 2; ++kk)
      qf[im][kk] = *reinterpret_cast<const bf16x8*>(
          qb + (rowbase + q0 + w * 32 + im * 16 + lr) * C_ + hoff + kk * 32 + lg * 8);

  f32x4 acc[2][4] = {};
  float m_run[2][4], l_run[2][4];
#pragma unroll
  for (int im = 0; im < 2; ++im)
#pragma unroll
    for (int j = 0; j < 4; ++j) { m_run[im][j] = -INFINITY; l_run[im][j] = 0.f; }

  __bf16* pb = Pls + w * (32 * 72);
  const int ntiles = q0 / 64 + 2;

  for (int t = 0; t < ntiles; ++t) {
    const int kv0 = t * 64;
    __syncthreads();  // previous tile's Vts/P reads done
    {  // stage V transposed
      const int trow = tid >> 2, dc = tid & 3;
      const __bf16* src = vb + (rowbase + kv0 + trow) * C_ + hoff + dc * 16;
      bf16x8 v0 = *reinterpret_cast<const bf16x8*>(src);
      bf16x8 v1 = *reinterpret_cast<const bf16x8*>(src + 8);
#pragma unroll
      for (int i = 0; i < 8; ++i) {
        Vts[(dc * 16 + i) * 72 + trow] = v0[i];
        Vts[(dc * 16 + 8 + i) * 72 + trow] = v1[i];
      }
    }
    // K fragments (B-operand) direct from global (L2-resident, reused by 16 q-blocks)
    bf16x8 kf[4][2];
#pragma unroll
    for (int cf = 0; cf < 4; ++cf)
#pragma unroll
      for (int kk = 0; kk < 2; ++kk)
        kf[cf][kk] = *reinterpret_cast<const bf16x8*>(
            kb + (rowbase + kv0 + cf * 16 + lr) * C_ + hoff + kk * 32 + lg * 8);
    __syncthreads();  // Vts ready

#pragma unroll
    for (int im = 0; im < 2; ++im) {
      f32x4 sv[4] = {};
#pragma unroll
      for (int kk = 0; kk < 2; ++kk)
#pragma unroll
        for (int cf = 0; cf < 4; ++cf)
          sv[cf] = __builtin_amdgcn_mfma_f32_16x16x32_bf16(qf[im][kk], kf[cf][kk], sv[cf], 0, 0, 0);
      const int rowg = q0 + w * 32 + im * 16 + lg * 4;
#pragma unroll
      for (int j = 0; j < 4; ++j) {
        // scale + causal mask
#pragma unroll
        for (int cf = 0; cf < 4; ++cf) {
          const int col = kv0 + cf * 16 + lr;
          sv[cf][j] = (col <= rowg + j) ? sv[cf][j] * scale : -INFINITY;
        }
        float mm = fmaxf(fmaxf(sv[0][j], sv[1][j]), fmaxf(sv[2][j], sv[3][j]));
#pragma unroll
        for (int off = 1; off < 16; off <<= 1) mm = fmaxf(mm, __shfl_xor(mm, off));
        const float mnew = fmaxf(m_run[im][j], mm);
        const float alpha = __expf(m_run[im][j] - mnew);
        float rs = 0.f;
#pragma unroll
        for (int cf = 0; cf < 4; ++cf) {
          const float p = __expf(sv[cf][j] - mnew);
          sv[cf][j] = p;
          rs += p;
        }
#pragma unroll
        for (int off = 1; off < 16; off <<= 1) rs += __shfl_xor(rs, off);
        l_run[im][j] = l_run[im][j] * alpha + rs;
        m_run[im][j] = mnew;
#pragma unroll
        for (int n = 0; n < 4; ++n) acc[im][n][j] *= alpha;
#pragma unroll
        for (int cf = 0; cf < 4; ++cf)
          pb[(im * 16 + lg * 4 + j) * 72 + cf * 16 + lr] = (__bf16)sv[cf][j];
      }
    }
    __syncthreads();  // P (and Vts) visible to whole block

    // PV: acc += P * V
    bf16x8 vf[4][2];
#pragma unroll
    for (int n = 0; n < 4; ++n)
#pragma unroll
      for (int ks = 0; ks < 2; ++ks)
        vf[n][ks] = *reinterpret_cast<const bf16x8*>(Vts + (n * 16 + lr) * 72 + ks * 32 + lg * 8);
#pragma unroll
    for (int im = 0; im < 2; ++im) {
      bf16x8 pa[2];
#pragma unroll
      for (int ks = 0; ks < 2; ++ks)
        pa[ks] = *reinterpret_cast<const bf16x8*>(pb + (im * 16 + lr) * 72 + ks * 32 + lg * 8);
#pragma unroll
      for (int n = 0; n < 4; ++n)
#pragma unroll
        for (int ks = 0; ks < 2; ++ks)
          acc[im][n] = __builtin_amdgcn_mfma_f32_16x16x32_bf16(pa[ks], vf[n][ks], acc[im][n], 0, 0, 0);
    }
  }

  // epilogue: out[b, t, h*64+d] = acc / l
#pragma unroll
  for (int im = 0; im < 2; ++im) {
    float rl[4];
#pragma unroll
    for (int j = 0; j < 4; ++j) rl[j] = 1.f / l_run[im][j];
#pragma unroll
    for (int n = 0; n < 4; ++n)
#pragma unroll
      for (int j = 0; j < 4; ++j)
        ao[(rowbase + q0 + w * 32 + im * 16 + lg * 4 + j) * C_ + hoff + n * 16 + lr] =
            (__bf16)(acc[im][n][j] * rl[j]);
  }
}

// ---------------------------------------------------------------- launch
extern "C" void kernel_launch(void* const* d_in, const int* in_sizes, int n_in,
                              void* d_out, int out_size, void* d_ws, size_t ws_size,
                              hipStream_t stream) {
  const float* x  = (const float*)d_in[0];
  const float* Wq = (const float*)d_in[1];
  const float* Wk = (const float*)d_in[2];
  const float* Wv = (const float*)d_in[3];
  const float* Wp = (const float*)d_in[4];
  const float* bp = (const float*)d_in[5];
  float* out = (float*)d_out;

  const int NX = B_ * T_ * C_;  // 8388608
  const int NW = C_ * C_;       // 1048576

  __bf16* xb  = (__bf16*)d_ws;
  __bf16* wqb = xb + NX;
  __bf16* wkb = wqb + NW;
  __bf16* wvb = wkb + NW;
  __bf16* wpb = wvb + NW;
  __bf16* qb  = wpb + NW;
  __bf16* kb  = qb + NX;
  __bf16* vb  = kb + NX;
  __bf16* aob = vb + NX;

  castk<<<NX / 1024, 256, 0, stream>>>(x, xb, NX);
  castk<<<NW / 1024, 256, 0, stream>>>(Wq, wqb, NW);
  castk<<<NW / 1024, 256, 0, stream>>>(Wk, wkb, NW);
  castk<<<NW / 1024, 256, 0, stream>>>(Wv, wvb, NW);
  castk<<<NW / 1024, 256, 0, stream>>>(Wp, wpb, NW);

  gemm_qkv<<<dim3(C_ / 128, (B_ * T_) / 128, 3), 256, 0, stream>>>(xb, wqb, wkb, wvb, qb, kb, vb);
  attn_fwd<<<dim3(T_ / 128, B_ * H_), 256, 0, stream>>>(qb, kb, vb, aob);
  gemm_proj<<<dim3(C_ / 128, (B_ * T_) / 128), 256, 0, stream>>>(aob, wpb, out, bp);
}

// Round 3
// 271.754 us; speedup vs baseline: 1.5123x; 1.5123x over previous
//
#include <hip/hip_runtime.h>
#include <cstdint>
#include <cstddef>

typedef __attribute__((ext_vector_type(8))) __bf16 bf16x8;
typedef __attribute__((ext_vector_type(4))) __bf16 bf16x4;
typedef __attribute__((ext_vector_type(4))) float f32x4;
typedef __attribute__((ext_vector_type(16))) float f32x16;
typedef __attribute__((ext_vector_type(4))) unsigned uint4v;

#define B_ 4
#define T_ 2048
#define C_ 1024
#define H_ 16
#define D_ 64

// ---------------------------------------------------------------- cast f32->bf16
__global__ __launch_bounds__(256) void castk(const float* __restrict__ in,
                                             __bf16* __restrict__ out, int n) {
  int i = (blockIdx.x * blockDim.x + threadIdx.x) * 4;
  if (i >= n) return;
  float4 f = *reinterpret_cast<const float4*>(in + i);
  bf16x4 o;
  o[0] = (__bf16)f.x; o[1] = (__bf16)f.y; o[2] = (__bf16)f.z; o[3] = (__bf16)f.w;
  *reinterpret_cast<bf16x4*>(out + i) = o;
}

// ---------------------------------------------------------------- async global->LDS
__device__ __forceinline__ void gload_lds16(const __bf16* g, __bf16* lds) {
  __builtin_amdgcn_global_load_lds(
      (const __attribute__((address_space(1))) void*)g,
      (__attribute__((address_space(3))) void*)lds, 16, 0, 0);
}

// ---------------------------------------------------------------- GEMM  C = A * Bt^T
// (unchanged — m97 structure, 128x128 tile, BK=64)
template <typename OUTT, bool BIAS>
__device__ __forceinline__ void gemm_bt_body(const __bf16* __restrict__ A,
                                             const __bf16* __restrict__ Bt,
                                             OUTT* __restrict__ Cp,
                                             const float* __restrict__ bias,
                                             int M, int N, int K) {
  constexpr int BK = 64;
  __shared__ __bf16 As[128 * BK];
  __shared__ __bf16 Bs[128 * BK];
  const int tid = threadIdx.x;
  const int w = tid >> 6, l = tid & 63;
  const int wr = w >> 1, wc = w & 1;
  const int lr = l & 15, lg = l >> 4;
  const int m0 = blockIdx.y * 128, n0 = blockIdx.x * 128;
  const int srow = l >> 3, scol = (l & 7) * 8;

  f32x4 acc[4][4] = {};

  for (int k0 = 0; k0 < K; k0 += BK) {
#pragma unroll
    for (int it = 0; it < 4; ++it) {
      const int c = w * 4 + it;
      gload_lds16(A + (size_t)(m0 + 8 * c + srow) * K + k0 + scol, As + c * 512);
      gload_lds16(Bt + (size_t)(n0 + 8 * c + srow) * K + k0 + scol, Bs + c * 512);
    }
    __syncthreads();
    bf16x8 af[4][2], bfv[4][2];
#pragma unroll
    for (int m = 0; m < 4; ++m)
#pragma unroll
      for (int kk = 0; kk < 2; ++kk)
        af[m][kk] = *reinterpret_cast<const bf16x8*>(As + (wr * 64 + m * 16 + lr) * BK + kk * 32 + lg * 8);
#pragma unroll
    for (int n = 0; n < 4; ++n)
#pragma unroll
      for (int kk = 0; kk < 2; ++kk)
        bfv[n][kk] = *reinterpret_cast<const bf16x8*>(Bs + (wc * 64 + n * 16 + lr) * BK + kk * 32 + lg * 8);
#pragma unroll
    for (int kk = 0; kk < 2; ++kk)
#pragma unroll
      for (int m = 0; m < 4; ++m)
#pragma unroll
        for (int n = 0; n < 4; ++n)
          acc[m][n] = __builtin_amdgcn_mfma_f32_16x16x32_bf16(af[m][kk], bfv[n][kk], acc[m][n], 0, 0, 0);
    __syncthreads();
  }
#pragma unroll
  for (int m = 0; m < 4; ++m)
#pragma unroll
    for (int n = 0; n < 4; ++n) {
      const int col = n0 + wc * 64 + n * 16 + lr;
      float bv = 0.f;
      if (BIAS) bv = bias[col];
#pragma unroll
      for (int j = 0; j < 4; ++j) {
        const int row = m0 + wr * 64 + m * 16 + lg * 4 + j;
        Cp[(size_t)row * N + col] = (OUTT)(acc[m][n][j] + bv);
      }
    }
}

__global__ __launch_bounds__(256) void gemm_qkv(const __bf16* __restrict__ xb,
    const __bf16* __restrict__ wq, const __bf16* __restrict__ wk, const __bf16* __restrict__ wv,
    __bf16* __restrict__ q, __bf16* __restrict__ k, __bf16* __restrict__ v) {
  const __bf16* W = (blockIdx.z == 0) ? wq : (blockIdx.z == 1) ? wk : wv;
  __bf16* O = (blockIdx.z == 0) ? q : (blockIdx.z == 1) ? k : v;
  gemm_bt_body<__bf16, false>(xb, W, O, nullptr, B_ * T_, C_, C_);
}

__global__ __launch_bounds__(256) void gemm_proj(const __bf16* __restrict__ ao,
    const __bf16* __restrict__ wp, float* __restrict__ out, const float* __restrict__ bp) {
  gemm_bt_body<float, true>(ao, wp, out, bp, B_ * T_, C_, C_);
}

// ---------------------------------------------------------------- V transpose
// v [B*T][C] (col = h*64+d)  ->  vt [B][H][D][T]. LDS-tiled, coalesced both sides.
__global__ __launch_bounds__(256) void transposeV(const __bf16* __restrict__ v,
                                                  __bf16* __restrict__ vt) {
  __shared__ __bf16 tile[64][72];  // [t][d], pad to break bank alignment
  const int t0 = blockIdx.x * 64;
  const int h = blockIdx.y, b = blockIdx.z;
  const int l = threadIdx.x;
  const int r = l >> 2, c8 = (l & 3) * 16;
  const __bf16* src = v + (size_t)(b * T_ + t0 + r) * C_ + h * 64 + c8;
  *reinterpret_cast<bf16x8*>(&tile[r][c8]) = *reinterpret_cast<const bf16x8*>(src);
  *reinterpret_cast<bf16x8*>(&tile[r][c8 + 8]) = *reinterpret_cast<const bf16x8*>(src + 8);
  __syncthreads();
  // write row d=r, cols t0+c8..: o[i] = V[t0+c8+i][r]
  __bf16* dst = vt + (size_t)((b * H_ + h) * 64 + r) * T_ + t0 + c8;
  bf16x8 o0, o1;
#pragma unroll
  for (int i = 0; i < 8; ++i) { o0[i] = tile[c8 + i][r]; o1[i] = tile[c8 + 8 + i][r]; }
  *reinterpret_cast<bf16x8*>(dst) = o0;
  *reinterpret_cast<bf16x8*>(dst + 8) = o1;
}

// ---------------------------------------------------------------- helpers
__device__ __forceinline__ unsigned pk2(float a, float b) {
  const unsigned short ua = __builtin_bit_cast(unsigned short, (__bf16)a);
  const unsigned short ub = __builtin_bit_cast(unsigned short, (__bf16)b);
  return (unsigned)ua | ((unsigned)ub << 16);
}

// ---------------------------------------------------------------- flash attention v3
// Swapped QK^T (S^T, q = lane col), in-reg softmax, P^T frags via shfl_xor(32),
// O^T = V^T * P^T with V^T fragments loaded directly from pre-transposed global.
// Per-wave independent; zero LDS, zero barriers. Wave handles q-blocks {qx,63-qx}.
//
// 32x32x16 layouts used (m74/m101-verified C/D; A/B per lane31=row/col, hi*8+e=k):
//   A frag: A[row=lane31][k=hi*8+e]     B frag: B[k=hi*8+e][col=lane31]
//   C/D:    col=lane31, row=(r&3)+8*(r>>2)+4*hi
__global__ __launch_bounds__(256) void attn_fwd(const __bf16* __restrict__ qb,
                                                const __bf16* __restrict__ kb,
                                                const __bf16* __restrict__ vt,
                                                __bf16* __restrict__ ao) {
  const int tid = threadIdx.x;
  const int w = tid >> 6, l = tid & 63;
  const int lane31 = l & 31, hi = l >> 5;
  const int b = blockIdx.y >> 4;
  const int qx = blockIdx.x * 4 + w;  // 0..31
  const size_t rowbase = (size_t)b * T_;
  const int hoff = (blockIdx.y & 15) * D_;
  const __bf16* vtb = vt + (size_t)blockIdx.y * 64 * T_;  // [d][t] for this (b,h)
  const float cs = 0.03125f;    // C^-0.5
  const float THRRAW = 177.0f;  // defer-max: exp arg bounded by 177/32=5.53 -> P<=256

  for (int phase = 0; phase < 2; ++phase) {
    const int qg = (phase ? 63 - qx : qx) * 32;
    const int ntiles = (qg >> 5) + 1;

    // Q fragments (B-operand): lane holds Q[qg+lane31][t4*16 + hi*8 + e]
    bf16x8 qf[4];
    {
      const __bf16* qp = qb + (rowbase + qg + lane31) * C_ + hoff + hi * 8;
#pragma unroll
      for (int t4 = 0; t4 < 4; ++t4)
        qf[t4] = *reinterpret_cast<const bf16x8*>(qp + t4 * 16);
    }

    f32x16 acc0 = {};  // O^T rows d 0..31 (col = q = lane31)
    f32x16 acc1 = {};  // O^T rows d 32..63
    float m_run = -INFINITY, l_run = 0.f;

    for (int t = 0; t < ntiles; ++t) {
      const int kv0 = t * 32;
      // K fragments (A-operand): lane holds K[kv0+lane31][t4*16 + hi*8 + e]
      const __bf16* kp = kb + (rowbase + kv0 + lane31) * C_ + hoff + hi * 8;
      bf16x8 kf[4];
#pragma unroll
      for (int t4 = 0; t4 < 4; ++t4)
        kf[t4] = *reinterpret_cast<const bf16x8*>(kp + t4 * 16);
      // V^T fragments (A-operand of PV): lane holds VT[dblk*32+lane31][kv0+ks*16+hi*8+e]
      const __bf16* vp = vtb + (size_t)lane31 * T_ + kv0 + hi * 8;
      bf16x8 vf[2][2];
#pragma unroll
      for (int dblk = 0; dblk < 2; ++dblk)
#pragma unroll
        for (int ks = 0; ks < 2; ++ks)
          vf[dblk][ks] = *reinterpret_cast<const bf16x8*>(vp + dblk * 32 * T_ + ks * 16);

      // S^T[kv][q] = K * Q^T : col=q=lane31, row kv=(r&3)+8*(r>>2)+4*hi
      f32x16 s = {};
#pragma unroll
      for (int t4 = 0; t4 < 4; ++t4)
        s = __builtin_amdgcn_mfma_f32_32x32x16_bf16(kf[t4], qf[t4], s, 0, 0, 0);

      float sv[16];
#pragma unroll
      for (int r = 0; r < 16; ++r) sv[r] = s[r];
      if (t == ntiles - 1) {  // diagonal tile: need kv_local <= q_local
#pragma unroll
        for (int r = 0; r < 16; ++r) {
          const int kvloc = (r & 3) + 8 * (r >> 2) + 4 * hi;
          sv[r] = (kvloc <= lane31) ? sv[r] : -1e30f;
        }
      }

      // online softmax in raw-score domain, scale folded into exp
      float mm = sv[0];
#pragma unroll
      for (int r = 1; r < 16; ++r) mm = fmaxf(mm, sv[r]);
      mm = fmaxf(mm, __shfl_xor(mm, 32));  // partner lane holds same q, other kv half
      if (mm > m_run + THRRAW) {           // defer-max (T13)
        const float alpha = __expf((m_run - mm) * cs);
#pragma unroll
        for (int r = 0; r < 16; ++r) { acc0[r] *= alpha; acc1[r] *= alpha; }
        l_run *= alpha;
        m_run = mm;
      }
      const float negm = -m_run * cs;
      float rs = 0.f;
#pragma unroll
      for (int r = 0; r < 16; ++r) {
        const float p = __expf(__builtin_fmaf(sv[r], cs, negm));
        sv[r] = p;
        rs += p;
      }
      rs += __shfl_xor(rs, 32);
      l_run += rs;

      // P^T B-fragments via shfl. Own packed words (lo-lane view / hi-lane view):
      //   X0=kv(0,1)/(4,5)  X1=kv(2,3)/(6,7)  Y0=kv(8,9)/(12,13)  Y1=kv(10,11)/(14,15)
      // Need word w of chunk ks = kv(ks*16+hi*8+2w, +1):
      //   w0: lo X0, hi sY0 | w1: lo X1, hi sY1 | w2: lo sX0, hi Y0 | w3: lo sX1, hi Y1
      unsigned pwv[8];
#pragma unroll
      for (int ks = 0; ks < 2; ++ks) {
        const unsigned X0 = pk2(sv[ks * 8 + 0], sv[ks * 8 + 1]);
        const unsigned X1 = pk2(sv[ks * 8 + 2], sv[ks * 8 + 3]);
        const unsigned Y0 = pk2(sv[ks * 8 + 4], sv[ks * 8 + 5]);
        const unsigned Y1 = pk2(sv[ks * 8 + 6], sv[ks * 8 + 7]);
        const unsigned sX0 = __shfl_xor(X0, 32);
        const unsigned sX1 = __shfl_xor(X1, 32);
        const unsigned sY0 = __shfl_xor(Y0, 32);
        const unsigned sY1 = __shfl_xor(Y1, 32);
        pwv[ks * 4 + 0] = hi ? sY0 : X0;
        pwv[ks * 4 + 1] = hi ? sY1 : X1;
        pwv[ks * 4 + 2] = hi ? Y0 : sX0;
        pwv[ks * 4 + 3] = hi ? Y1 : sX1;
      }
      const uint4v u0 = {pwv[0], pwv[1], pwv[2], pwv[3]};
      const uint4v u1 = {pwv[4], pwv[5], pwv[6], pwv[7]};
      const bf16x8 pf0 = __builtin_bit_cast(bf16x8, u0);
      const bf16x8 pf1 = __builtin_bit_cast(bf16x8, u1);

      // O^T += V^T * P^T
      acc0 = __builtin_amdgcn_mfma_f32_32x32x16_bf16(vf[0][0], pf0, acc0, 0, 0, 0);
      acc0 = __builtin_amdgcn_mfma_f32_32x32x16_bf16(vf[0][1], pf1, acc0, 0, 0, 0);
      acc1 = __builtin_amdgcn_mfma_f32_32x32x16_bf16(vf[1][0], pf0, acc1, 0, 0, 0);
      acc1 = __builtin_amdgcn_mfma_f32_32x32x16_bf16(vf[1][1], pf1, acc1, 0, 0, 0);
    }

    // epilogue: O[q][d] = O^T[d][q]/l ; d = dblk*32 + qd*8 + hi*4 + j
    const float rl = 1.0f / l_run;
    __bf16* op = ao + (rowbase + qg + lane31) * C_ + hoff + hi * 4;
#pragma unroll
    for (int dblk = 0; dblk < 2; ++dblk)
#pragma unroll
      for (int qd = 0; qd < 4; ++qd) {
        bf16x4 ov;
#pragma unroll
        for (int j = 0; j < 4; ++j) {
          const float av = (dblk == 0) ? acc0[qd * 4 + j] : acc1[qd * 4 + j];
          ov[j] = (__bf16)(av * rl);
        }
        *reinterpret_cast<bf16x4*>(op + dblk * 32 + qd * 8) = ov;
      }
  }
}

// ---------------------------------------------------------------- launch
extern "C" void kernel_launch(void* const* d_in, const int* in_sizes, int n_in,
                              void* d_out, int out_size, void* d_ws, size_t ws_size,
                              hipStream_t stream) {
  const float* x  = (const float*)d_in[0];
  const float* Wq = (const float*)d_in[1];
  const float* Wk = (const float*)d_in[2];
  const float* Wv = (const float*)d_in[3];
  const float* Wp = (const float*)d_in[4];
  const float* bp = (const float*)d_in[5];
  float* out = (float*)d_out;

  const int NX = B_ * T_ * C_;
  const int NW = C_ * C_;

  __bf16* xb  = (__bf16*)d_ws;
  __bf16* wqb = xb + NX;
  __bf16* wkb = wqb + NW;
  __bf16* wvb = wkb + NW;
  __bf16* wpb = wvb + NW;
  __bf16* qb  = wpb + NW;
  __bf16* kb  = qb + NX;
  __bf16* vb  = kb + NX;
  __bf16* aob = vb + NX;
  __bf16* vtb = xb;  // xb is dead after gemm_qkv; reuse as V^T [B][H][D][T]

  castk<<<NX / 1024, 256, 0, stream>>>(x, xb, NX);
  castk<<<NW / 1024, 256, 0, stream>>>(Wq, wqb, NW);
  castk<<<NW / 1024, 256, 0, stream>>>(Wk, wkb, NW);
  castk<<<NW / 1024, 256, 0, stream>>>(Wv, wvb, NW);
  castk<<<NW / 1024, 256, 0, stream>>>(Wp, wpb, NW);

  gemm_qkv<<<dim3(C_ / 128, (B_ * T_) / 128, 3), 256, 0, stream>>>(xb, wqb, wkb, wvb, qb, kb, vb);
  transposeV<<<dim3(T_ / 64, H_, B_), 256, 0, stream>>>(vb, vtb);
  attn_fwd<<<dim3(8, B_ * H_), 256, 0, stream>>>(qb, kb, vtb, aob);
  gemm_proj<<<dim3(C_ / 128, (B_ * T_) / 128), 256, 0, stream>>>(aob, wpb, out, bp);
}